// Round 4
// baseline (335.063 us; speedup 1.0000x reference)
//
#include <hip/hip_runtime.h>
#include <hip/hip_cooperative_groups.h>
#include <math.h>

namespace cg = cooperative_groups;

#define B_ 64
#define E_ 256
#define S_ 32
#define H_ 16
#define P_ 512
#define KC_ 46
#define QKV_N (B_*S_*E_)   // 524288 floats per Q/K/V region

// workspace float offsets (float4-aligned)
#define WS_CM     0        // 64    key multiplicities
#define WS_WK     256      // 2944  Wk[64][46] per-row class weights
#define WS_INVDEN 3328     // 1
#define WS_C      3392     // 46    logit constant c[k]
#define WS_M      3584     // 11776 M[46][256] = Hw @ Wout
#define WS_WT     16384    // 196608 WT[256][768] transposed in_proj_w
#define WS_QKV    262144   // 3*524288
#define WS_OPART  1835008  // 524288 O_part[32][16][64][16]  (s,h,a,d)

// One cooperative kernel, 512 blocks x 256 threads, 4 phases:
//  P0 prep (WT transpose | pair setup | M,c | zero out)  -> grid.sync
//  P1 QKV projection (uniform 2 blocks/CU)               -> grid.sync
//  P2 weighted attention per (s,h), 31KB LDS             -> grid.sync
//  P3 logits + lse + weighted-CE (blocks 0..63)
__global__ __launch_bounds__(256) void k_fused(
    const float* __restrict__ feat, const int* __restrict__ labels0,
    const int* __restrict__ labels1, const float* __restrict__ ipw,
    const float* __restrict__ ipb, const float* __restrict__ opw,
    const float* __restrict__ opb, const float* __restrict__ fw,
    const float* __restrict__ fbi, const float* __restrict__ hw,
    const float* __restrict__ hb, float* ws, float* out) {
  __shared__ float sm[8192];           // 32 KB, reused per phase
  cg::grid_group grid = cg::this_grid();
  const int bid = blockIdx.x, t = threadIdx.x;

  // ================= P0: prep =================
  if (bid < 48) {
    // transpose in_proj_w [768][256] -> WT[256][768], 64x64 LDS tile
    const int r0 = (bid >> 2) * 64, c0 = (bid & 3) * 64;
    float* ts = sm;                    // 64 x 65
#pragma unroll
    for (int p = 0; p < 4; ++p) {
      int r = p*16 + (t >> 4), c4 = t & 15;
      float4 v = *(const float4*)(ipw + (size_t)(r0+r)*E_ + c0 + c4*4);
      ts[(c4*4+0)*65 + r] = v.x;
      ts[(c4*4+1)*65 + r] = v.y;
      ts[(c4*4+2)*65 + r] = v.z;
      ts[(c4*4+3)*65 + r] = v.w;
    }
    __syncthreads();
    float* WT = ws + WS_WT;
#pragma unroll
    for (int p = 0; p < 4; ++p) {
      int c = p*16 + (t >> 4), r4 = t & 15;
      float4 v = make_float4(ts[c*65 + r4*4], ts[c*65 + r4*4 + 1],
                             ts[c*65 + r4*4 + 2], ts[c*65 + r4*4 + 3]);
      *(float4*)(WT + (size_t)(c0+c)*768 + r0 + r4*4) = v;
    }
  } else if (bid == 48) {
    // pair selection, class ids, Wk, cm, inv_den
    float* csh = sm;                  // 64
    float* cls = sm + 64;             // 46
    float* wsh = sm + 112;            // 46
    float* den = sm + 160;            // 1
    float* Wk  = sm + 192;            // 2944
    int* scan = (int*)(sm + 3200);    // 256
    int* l0   = (int*)(sm + 3456);    // 64
    int* l1   = (int*)(sm + 3520);    // 64
    int* seli = (int*)(sm + 3584);    // 512
    int* selj = (int*)(sm + 4096);    // 512
    if (t < 64) { l0[t] = labels0[t]; l1[t] = labels1[t]; csh[t] = 0.f; }
    if (t < KC_) cls[t] = 0.f;
    if (t == 0) den[0] = 0.f;
    for (int i = t; i < 2944; i += 256) Wk[i] = 0.f;
    __syncthreads();
    unsigned bits = 0; int c = 0;
    for (int u = 0; u < 16; ++u) {    // contiguous 16-chunk keeps row-major order
      int idx = t*16 + u;
      if (l1[idx>>6] == l1[idx&63]) { bits |= 1u<<u; ++c; }
    }
    scan[t] = c; __syncthreads();
    for (int off = 1; off < 256; off <<= 1) {
      int v = (t >= off) ? scan[t-off] : 0;
      __syncthreads();
      scan[t] += v;
      __syncthreads();
    }
    const int total = scan[255];
    int rank = scan[t] - c;           // exclusive prefix
    for (int p = t; p < P_; p += 256)
      if (p >= total) { seli[p] = 0; selj[p] = 0; }   // fill_value=0
    for (int u = 0; u < 16; ++u) {
      if (bits & (1u<<u)) {
        if (rank < P_) { int idx = t*16+u; seli[rank] = idx>>6; selj[rank] = idx&63; }
        ++rank;
      }
    }
    __syncthreads();
    int ii[2], yy[2]; float vv[2];
#pragma unroll
    for (int r = 0; r < 2; ++r) {
      int p = t + r*256;
      int i = seli[p], j = selj[p];
      atomicAdd(&csh[j], 1.0f);       // multiplicity incl. padding pairs
      int la = l0[i], lb = l0[j];
      int y;
      if (la == lb) y = 0;
      else {
        int lo = la < lb ? la : lb, hi = la < lb ? lb : la;
        y = 1 + lo*9 - (lo*(lo-1))/2 + (hi-lo-1);
      }
      float v = (p < total) ? 1.f : 0.f;
      if (v > 0.f) atomicAdd(&cls[y], 1.f);
      ii[r] = i; yy[r] = y; vv[r] = v;
    }
    __syncthreads();
    if (t < KC_) {
      float cv = cls[t];
      wsh[t] = cv > 0.f ? 1.0f/cv : 0.f;
      if (cv > 0.f) atomicAdd(den, 1.0f);   // sum(wy) == #present classes
    }
    __syncthreads();
#pragma unroll
    for (int r = 0; r < 2; ++r)
      if (vv[r] > 0.f) atomicAdd(&Wk[ii[r]*KC_ + yy[r]], wsh[yy[r]]);
    __syncthreads();
    if (t < 64) ws[WS_CM + t] = csh[t];
    for (int i = t; i < 2944; i += 256) ws[WS_WK + i] = Wk[i];
    if (t == 0) ws[WS_INVDEN] = 1.0f / den[0];
  } else if (bid < 95) {
    // M[k,:] = hw[k,:] @ Wout  and  c[k]
    int k = bid - 49;
    float* hwsh = sm;                 // 256
    float* redA = sm + 256;           // 256
    float* redB = sm + 512;           // 256
    hwsh[t] = hw[k*E_ + t];
    __syncthreads();
    float a0 = 0.f;
#pragma unroll 8
    for (int e = 0; e < E_; ++e) a0 = fmaf(hwsh[e], opw[e*E_ + t], a0);
    ws[WS_M + k*E_ + t] = a0;
    redA[t] = hwsh[t];
    redB[t] = hwsh[t]*opb[t];
    __syncthreads();
    for (int off = 128; off > 0; off >>= 1) {
      if (t < off) { redA[t] += redA[t+off]; redB[t] += redB[t+off]; }
      __syncthreads();
    }
    if (t == 0) {
      float sfw = 0.f;
      for (int s = 0; s < S_; ++s) sfw += fw[s];
      ws[WS_C + k] = fbi[0]*redA[0] + sfw*redB[0] + hb[k];
    }
  } else if (bid == 95) {
    if (t == 0) out[0] = 0.f;
  }
  grid.sync();

  // ================= P1: QKV projection =================
  {
    const int b = bid >> 3, oc = bid & 7;        // 64 b x 8 out-chunks of 96
    const float4* fb4 = (const float4*)(feat + (size_t)b*(E_*S_));
    float4* xs4 = (float4*)sm;
#pragma unroll
    for (int i = 0; i < 8; ++i) xs4[i*256 + t] = fb4[i*256 + t];
    __syncthreads();
    const int s = t & 31, to8 = t >> 5;          // 8 out-groups x 32 s (all active)
    const int out0 = oc*96 + to8*12;
    const float4* WT4 = (const float4*)(ws + WS_WT);
    const int wbase = out0 >> 2;                  // float4 index in 192-wide row
    float acc[12];
#pragma unroll
    for (int i = 0; i < 12; ++i) acc[i] = 0.f;
#pragma unroll 4
    for (int e = 0; e < E_; ++e) {
      float xv = sm[e*32 + s];                    // same-address broadcast per wave
      float4 w0 = WT4[e*192 + wbase];
      float4 w1 = WT4[e*192 + wbase + 1];
      float4 w2 = WT4[e*192 + wbase + 2];
      acc[0] = fmaf(w0.x, xv, acc[0]);  acc[1] = fmaf(w0.y, xv, acc[1]);
      acc[2] = fmaf(w0.z, xv, acc[2]);  acc[3] = fmaf(w0.w, xv, acc[3]);
      acc[4] = fmaf(w1.x, xv, acc[4]);  acc[5] = fmaf(w1.y, xv, acc[5]);
      acc[6] = fmaf(w1.z, xv, acc[6]);  acc[7] = fmaf(w1.w, xv, acc[7]);
      acc[8] = fmaf(w2.x, xv, acc[8]);  acc[9] = fmaf(w2.y, xv, acc[9]);
      acc[10] = fmaf(w2.z, xv, acc[10]); acc[11] = fmaf(w2.w, xv, acc[11]);
    }
#pragma unroll
    for (int g = 0; g < 3; ++g) {
      int og = out0 + g*4;                        // 4-aligned, never crosses r
      float4 bb = *(const float4*)(ipb + og);
      int r = og >> 8, e_in = og & 255;
      float* dst = ws + WS_QKV + (size_t)r*QKV_N + (size_t)b*(S_*E_) + s*E_ + e_in;
      *(float4*)dst = make_float4(acc[g*4+0]+bb.x, acc[g*4+1]+bb.y,
                                  acc[g*4+2]+bb.z, acc[g*4+3]+bb.w);
    }
  }
  grid.sync();

  // ================= P2: weighted attention per (s,h) =================
  {
    float* qT = sm;                   // 16*68
    float* kT = sm + 1088;            // 16*68
    float* vs = sm + 2176;            // 64*20
    float* sc = sm + 3456;            // 64*68 (scores -> P in-place)
    float* cm = sm + 7808;            // 64    (total 7872 < 8192)
    const int s = bid >> 4, h = bid & 15;
    const int a = t >> 2, dq = t & 3;
    const float* qkv = ws + WS_QKV;
    {
      size_t off = (size_t)a*(S_*E_) + (size_t)s*E_ + h*16 + dq*4;
      float4 q4 = *(const float4*)(qkv + off);
      float4 k4 = *(const float4*)(qkv + QKV_N + off);
      float4 v4 = *(const float4*)(qkv + 2*(size_t)QKV_N + off);
      qT[(dq*4+0)*68 + a] = q4.x; qT[(dq*4+1)*68 + a] = q4.y;
      qT[(dq*4+2)*68 + a] = q4.z; qT[(dq*4+3)*68 + a] = q4.w;
      kT[(dq*4+0)*68 + a] = k4.x; kT[(dq*4+1)*68 + a] = k4.y;
      kT[(dq*4+2)*68 + a] = k4.z; kT[(dq*4+3)*68 + a] = k4.w;
      *(float4*)(vs + a*20 + dq*4) = v4;
    }
    if (t < 64) cm[t] = ws[WS_CM + t];
    __syncthreads();
    // scores: 4x4 register outer product -> sc[a][b]
    {
      const int ta = t & 15, tb = t >> 4;
      float sa[4][4];
#pragma unroll
      for (int r = 0; r < 4; ++r)
#pragma unroll
        for (int c = 0; c < 4; ++c) sa[r][c] = 0.f;
#pragma unroll
      for (int d = 0; d < 16; ++d) {
        float4 qv = *(float4*)(qT + d*68 + ta*4);
        float4 kv = *(float4*)(kT + d*68 + tb*4);
        float qr[4] = {qv.x,qv.y,qv.z,qv.w};
        float kc[4] = {kv.x,kv.y,kv.z,kv.w};
#pragma unroll
        for (int r = 0; r < 4; ++r)
#pragma unroll
          for (int c = 0; c < 4; ++c) sa[r][c] = fmaf(qr[r], kc[c], sa[r][c]);
      }
#pragma unroll
      for (int r = 0; r < 4; ++r)
        *(float4*)(sc + (ta*4+r)*68 + tb*4) =
            make_float4(sa[r][0]*0.25f, sa[r][1]*0.25f,
                        sa[r][2]*0.25f, sa[r][3]*0.25f);
    }
    __syncthreads();
    // weighted softmax row a, normalized IN-PLACE in sc
    {
      float pv[16], cmv[16];
#pragma unroll
      for (int i4 = 0; i4 < 4; ++i4) {
        float4 v = *(float4*)(sc + a*68 + dq*16 + i4*4);
        pv[i4*4+0] = v.x; pv[i4*4+1] = v.y; pv[i4*4+2] = v.z; pv[i4*4+3] = v.w;
      }
#pragma unroll
      for (int i = 0; i < 16; ++i) cmv[i] = cm[dq*16 + i];
      float Mx = -1e30f;
#pragma unroll
      for (int i = 0; i < 16; ++i) if (cmv[i] > 0.f) Mx = fmaxf(Mx, pv[i]);
      Mx = fmaxf(Mx, __shfl_xor(Mx, 1));
      Mx = fmaxf(Mx, __shfl_xor(Mx, 2));
      float z = 0.f;
#pragma unroll
      for (int i = 0; i < 16; ++i) {
        float e = (cmv[i] > 0.f) ? cmv[i]*__expf(pv[i]-Mx) : 0.f;
        pv[i] = e; z += e;
      }
      z += __shfl_xor(z, 1);
      z += __shfl_xor(z, 2);
      float rz = 1.0f / z;
#pragma unroll
      for (int i4 = 0; i4 < 4; ++i4)
        *(float4*)(sc + a*68 + dq*16 + i4*4) =
            make_float4(pv[i4*4+0]*rz, pv[i4*4+1]*rz,
                        pv[i4*4+2]*rz, pv[i4*4+3]*rz);
    }
    __syncthreads();
    // PV: wave g owns rows g*16..g*16+15; lane quad spans d
    {
      const int g = t >> 6, l = t & 63;
      const int ar = g*16 + (l >> 2), d4 = (l & 3)*4;
      float o0 = 0.f, o1 = 0.f, o2 = 0.f, o3 = 0.f;
#pragma unroll 4
      for (int b4 = 0; b4 < 64; b4 += 4) {
        float4 p4 = *(float4*)(sc + ar*68 + b4);
        float4 va = *(float4*)(vs + (b4+0)*20 + d4);
        float4 vb = *(float4*)(vs + (b4+1)*20 + d4);
        float4 vc = *(float4*)(vs + (b4+2)*20 + d4);
        float4 vd = *(float4*)(vs + (b4+3)*20 + d4);
        o0 = fmaf(p4.x, va.x, fmaf(p4.y, vb.x, fmaf(p4.z, vc.x, fmaf(p4.w, vd.x, o0))));
        o1 = fmaf(p4.x, va.y, fmaf(p4.y, vb.y, fmaf(p4.z, vc.y, fmaf(p4.w, vd.y, o1))));
        o2 = fmaf(p4.x, va.z, fmaf(p4.y, vb.z, fmaf(p4.z, vc.z, fmaf(p4.w, vd.z, o2))));
        o3 = fmaf(p4.x, va.w, fmaf(p4.y, vb.w, fmaf(p4.z, vc.w, fmaf(p4.w, vd.w, o3))));
      }
      const float fwS = fw[s];
      // O_part[s][h][ar][d4]: block-contiguous 4KB, lane-contiguous float4s
      float* dst = ws + WS_OPART + (size_t)s*(H_*B_*16) + h*(B_*16) + t*4;
      *(float4*)dst = make_float4(fwS*o0, fwS*o1, fwS*o2, fwS*o3);
    }
  }
  grid.sync();

  // ================= P3: logits + lse + weighted-CE (blocks 0..63) ========
  if (bid < 64) {
    const int aa = bid;
    float* oh = sm;                   // 256
    float* lg = sm + 256;             // 64
    {
      const float* op = ws + WS_OPART + (t>>4)*(B_*16) + aa*16 + (t&15);
      float acc = 0.f;
#pragma unroll
      for (int s = 0; s < S_; ++s) acc += op[(size_t)s*(H_*B_*16)];
      oh[t] = acc;
    }
    __syncthreads();
    const int k = t >> 2, q = t & 3;
    if (k < KC_) {
      float lv = 0.f;
      const float4* M4 = (const float4*)(ws + WS_M + k*E_ + q*64);
      const float4* o4 = (const float4*)(oh + q*64);
#pragma unroll
      for (int j = 0; j < 16; ++j) {
        float4 m = M4[j], o = o4[j];
        lv = fmaf(m.x, o.x, lv); lv = fmaf(m.y, o.y, lv);
        lv = fmaf(m.z, o.z, lv); lv = fmaf(m.w, o.w, lv);
      }
      lv += __shfl_xor(lv, 1);
      lv += __shfl_xor(lv, 2);
      if (q == 0) lg[k] = lv + ws[WS_C + k];
    }
    __syncthreads();
    if (t < 64) {
      float x = (t < KC_) ? lg[t] : -1e30f;
      float Mx = x;
#pragma unroll
      for (int off = 1; off < 64; off <<= 1) Mx = fmaxf(Mx, __shfl_xor(Mx, off));
      float z = (t < KC_) ? __expf(x - Mx) : 0.f;
#pragma unroll
      for (int off = 1; off < 64; off <<= 1) z += __shfl_xor(z, off);
      float lse = Mx + __logf(z);
      float term = (t < KC_) ? ws[WS_WK + aa*KC_ + t] * (lse - x) : 0.f;
#pragma unroll
      for (int off = 1; off < 64; off <<= 1) term += __shfl_xor(term, off);
      if (t == 0) atomicAdd(out, term * ws[WS_INVDEN]);
    }
  }
}

extern "C" void kernel_launch(void* const* d_in, const int* in_sizes, int n_in,
                              void* d_out, int out_size, void* d_ws, size_t ws_size,
                              hipStream_t stream) {
  const float* feat    = (const float*)d_in[0];
  const int*   labels0 = (const int*)d_in[1];
  const int*   labels1 = (const int*)d_in[2];
  const float* ipw     = (const float*)d_in[3];
  const float* ipb     = (const float*)d_in[4];
  const float* opw     = (const float*)d_in[5];
  const float* opb     = (const float*)d_in[6];
  const float* fw      = (const float*)d_in[7];
  const float* fbi     = (const float*)d_in[8];
  const float* hw      = (const float*)d_in[9];
  const float* hb      = (const float*)d_in[10];
  float* out = (float*)d_out;
  float* ws  = (float*)d_ws;

  void* args[] = {(void*)&feat, (void*)&labels0, (void*)&labels1, (void*)&ipw,
                  (void*)&ipb, (void*)&opw, (void*)&opb, (void*)&fw,
                  (void*)&fbi, (void*)&hw, (void*)&hb, (void*)&ws, (void*)&out};
  hipLaunchCooperativeKernel((void*)k_fused, dim3(512), dim3(256), args, 0, stream);
}

// Round 5
// 146.671 us; speedup vs baseline: 2.2845x; 2.2845x over previous
//
#include <hip/hip_runtime.h>
#include <math.h>

#define B_ 64
#define E_ 256
#define S_ 32
#define H_ 16
#define P_ 512
#define KC_ 46
#define QKV_N (B_*S_*E_)   // 524288 floats per Q/K/V region

// workspace float offsets (float4-aligned)
#define WS_CM     0        // 64    key multiplicities
#define WS_WK     256      // 2944  Wk[64][46] per-row class weights
#define WS_INVDEN 3328     // 1
#define WS_C      3392     // 46    logit constant c[k]
#define WS_M      3584     // 11776 M[46][256] = Hw @ Wout
#define WS_WT     16384    // 196608 WT[256][768] transposed in_proj_w
#define WS_QKV    262144   // 3*524288
#define WS_OPART  1835008  // 524288 O_part[32][16][64][16]  (s,h,a,d)

// ============ K0: prep (WT transpose | pair setup | M,c | zero out) ========
__global__ __launch_bounds__(256) void k_prep(
    const float* __restrict__ w, const int* __restrict__ labels0,
    const int* __restrict__ labels1, const float* __restrict__ wout,
    const float* __restrict__ bout, const float* __restrict__ fw,
    const float* __restrict__ fbi, const float* __restrict__ hw,
    const float* __restrict__ hb, float* __restrict__ ws,
    float* __restrict__ out) {
  __shared__ float sm[8192];
  const int bid = blockIdx.x, t = threadIdx.x;
  if (bid < 48) {
    // transpose in_proj_w [768][256] -> WT[256][768], 64x64 LDS tile
    const int r0 = (bid >> 2) * 64, c0 = (bid & 3) * 64;
    float* ts = sm;                               // 64 x 65
#pragma unroll
    for (int p = 0; p < 4; ++p) {
      int r = p*16 + (t >> 4), c4 = t & 15;
      float4 v = *(const float4*)(w + (size_t)(r0+r)*E_ + c0 + c4*4);
      ts[(c4*4+0)*65 + r] = v.x;
      ts[(c4*4+1)*65 + r] = v.y;
      ts[(c4*4+2)*65 + r] = v.z;
      ts[(c4*4+3)*65 + r] = v.w;
    }
    __syncthreads();
    float* WT = ws + WS_WT;
#pragma unroll
    for (int p = 0; p < 4; ++p) {
      int c = p*16 + (t >> 4), r4 = t & 15;
      float4 v = make_float4(ts[c*65 + r4*4], ts[c*65 + r4*4 + 1],
                             ts[c*65 + r4*4 + 2], ts[c*65 + r4*4 + 3]);
      *(float4*)(WT + (size_t)(c0+c)*768 + r0 + r4*4) = v;
    }
  } else if (bid == 48) {
    // pair selection, class ids, Wk, cm, inv_den
    float* csh = sm;                  // 64
    float* cls = sm + 64;             // 46
    float* wsh = sm + 112;            // 46
    float* den = sm + 160;            // 1
    float* Wk  = sm + 192;            // 2944
    int* scan = (int*)(sm + 3200);    // 256
    int* l0   = (int*)(sm + 3456);    // 64
    int* l1   = (int*)(sm + 3520);    // 64
    int* seli = (int*)(sm + 3584);    // 512
    int* selj = (int*)(sm + 4096);    // 512
    if (t < 64) { l0[t] = labels0[t]; l1[t] = labels1[t]; csh[t] = 0.f; }
    if (t < KC_) cls[t] = 0.f;
    if (t == 0) den[0] = 0.f;
    for (int i = t; i < 2944; i += 256) Wk[i] = 0.f;
    __syncthreads();
    unsigned bits = 0; int c = 0;
    for (int u = 0; u < 16; ++u) {    // contiguous 16-chunk keeps row-major order
      int idx = t*16 + u;
      if (l1[idx>>6] == l1[idx&63]) { bits |= 1u<<u; ++c; }
    }
    scan[t] = c; __syncthreads();
    for (int off = 1; off < 256; off <<= 1) {
      int v = (t >= off) ? scan[t-off] : 0;
      __syncthreads();
      scan[t] += v;
      __syncthreads();
    }
    const int total = scan[255];
    int rank = scan[t] - c;           // exclusive prefix
    for (int p = t; p < P_; p += 256)
      if (p >= total) { seli[p] = 0; selj[p] = 0; }   // fill_value=0
    for (int u = 0; u < 16; ++u) {
      if (bits & (1u<<u)) {
        if (rank < P_) { int idx = t*16+u; seli[rank] = idx>>6; selj[rank] = idx&63; }
        ++rank;
      }
    }
    __syncthreads();
    int ii[2], yy[2]; float vv[2];
#pragma unroll
    for (int r = 0; r < 2; ++r) {
      int p = t + r*256;
      int i = seli[p], j = selj[p];
      atomicAdd(&csh[j], 1.0f);       // multiplicity incl. padding pairs
      int la = l0[i], lb = l0[j];
      int y;
      if (la == lb) y = 0;
      else {
        int lo = la < lb ? la : lb, hi = la < lb ? lb : la;
        y = 1 + lo*9 - (lo*(lo-1))/2 + (hi-lo-1);
      }
      float v = (p < total) ? 1.f : 0.f;
      if (v > 0.f) atomicAdd(&cls[y], 1.f);
      ii[r] = i; yy[r] = y; vv[r] = v;
    }
    __syncthreads();
    if (t < KC_) {
      float cv = cls[t];
      wsh[t] = cv > 0.f ? 1.0f/cv : 0.f;
      if (cv > 0.f) atomicAdd(den, 1.0f);   // sum(wy) == #present classes
    }
    __syncthreads();
#pragma unroll
    for (int r = 0; r < 2; ++r)
      if (vv[r] > 0.f) atomicAdd(&Wk[ii[r]*KC_ + yy[r]], wsh[yy[r]]);
    __syncthreads();
    if (t < 64) ws[WS_CM + t] = csh[t];
    for (int i = t; i < 2944; i += 256) ws[WS_WK + i] = Wk[i];
    if (t == 0) ws[WS_INVDEN] = 1.0f / den[0];
  } else if (bid < 95) {
    // M[k,:] = hw[k,:] @ Wout  and  c[k]
    int k = bid - 49;
    float* hwsh = sm;                 // 256
    float* redA = sm + 256;           // 256
    float* redB = sm + 512;           // 256
    hwsh[t] = hw[k*E_ + t];
    __syncthreads();
    float a0 = 0.f;
#pragma unroll 8
    for (int e = 0; e < E_; ++e) a0 = fmaf(hwsh[e], wout[e*E_ + t], a0);
    ws[WS_M + k*E_ + t] = a0;
    redA[t] = hwsh[t];
    redB[t] = hwsh[t]*bout[t];
    __syncthreads();
    for (int off = 128; off > 0; off >>= 1) {
      if (t < off) { redA[t] += redA[t+off]; redB[t] += redB[t+off]; }
      __syncthreads();
    }
    if (t == 0) {
      float sfw = 0.f;
      for (int s = 0; s < S_; ++s) sfw += fw[s];
      ws[WS_C + k] = fbi[0]*redA[0] + sfw*redB[0] + hb[k];
    }
  } else {
    if (t == 0) out[0] = 0.f;
  }
}

// ============ K1: QKV projection, balanced 512 blocks (2/CU) ===============
// grid 512 = 64 b x 8 out-chunks of 96; thread = 12 outs x 1 s; X in LDS
__global__ __launch_bounds__(256) void k_proj(
    const float* __restrict__ feat, const float* __restrict__ bias,
    float* __restrict__ ws) {
  __shared__ float sm[E_*S_];                     // X[e][s], 32 KB
  const int bid = blockIdx.x, t = threadIdx.x;
  const int b = bid >> 3, oc = bid & 7;
  const float4* fb4 = (const float4*)(feat + (size_t)b*(E_*S_));
  float4* xs4 = (float4*)sm;
#pragma unroll
  for (int i = 0; i < 8; ++i) xs4[i*256 + t] = fb4[i*256 + t];
  __syncthreads();
  const int s = t & 31, to8 = t >> 5;             // 8 out-groups x 32 s
  const int out0 = oc*96 + to8*12;
  const float4* WT4 = (const float4*)(ws + WS_WT);
  const int wbase = out0 >> 2;                    // float4 index in 192-wide row
  float acc[12];
#pragma unroll
  for (int i = 0; i < 12; ++i) acc[i] = 0.f;
#pragma unroll 4
  for (int e = 0; e < E_; ++e) {
    float xv = sm[e*32 + s];                      // broadcast within lane group
    float4 w0 = WT4[e*192 + wbase];
    float4 w1 = WT4[e*192 + wbase + 1];
    float4 w2 = WT4[e*192 + wbase + 2];
    acc[0] = fmaf(w0.x, xv, acc[0]);  acc[1] = fmaf(w0.y, xv, acc[1]);
    acc[2] = fmaf(w0.z, xv, acc[2]);  acc[3] = fmaf(w0.w, xv, acc[3]);
    acc[4] = fmaf(w1.x, xv, acc[4]);  acc[5] = fmaf(w1.y, xv, acc[5]);
    acc[6] = fmaf(w1.z, xv, acc[6]);  acc[7] = fmaf(w1.w, xv, acc[7]);
    acc[8] = fmaf(w2.x, xv, acc[8]);  acc[9] = fmaf(w2.y, xv, acc[9]);
    acc[10] = fmaf(w2.z, xv, acc[10]); acc[11] = fmaf(w2.w, xv, acc[11]);
  }
#pragma unroll
  for (int g = 0; g < 3; ++g) {
    int og = out0 + g*4;                          // 4-aligned, same r always
    float4 bb = *(const float4*)(bias + og);
    int r = og >> 8, e_in = og & 255;
    float* dst = ws + WS_QKV + (size_t)r*QKV_N + (size_t)b*(S_*E_) + s*E_ + e_in;
    *(float4*)dst = make_float4(acc[g*4+0]+bb.x, acc[g*4+1]+bb.y,
                                acc[g*4+2]+bb.z, acc[g*4+3]+bb.w);
  }
}

// ============ K2: weighted attention per (s,h); exclusive O_part ===========
__global__ __launch_bounds__(256) void k_attn(
    float* __restrict__ ws, const float* __restrict__ fw) {
  __shared__ float qT[16*68], kT[16*68], vs[64*20], sc[64*68], cm[64];
  const int s = blockIdx.x >> 4, h = blockIdx.x & 15;
  const int t = threadIdx.x;
  const int a = t >> 2, dq = t & 3;
  const float* qkv = ws + WS_QKV;
  {
    size_t off = (size_t)a*(S_*E_) + (size_t)s*E_ + h*16 + dq*4;
    float4 q4 = *(const float4*)(qkv + off);
    float4 k4 = *(const float4*)(qkv + QKV_N + off);
    float4 v4 = *(const float4*)(qkv + 2*(size_t)QKV_N + off);
    qT[(dq*4+0)*68 + a] = q4.x; qT[(dq*4+1)*68 + a] = q4.y;
    qT[(dq*4+2)*68 + a] = q4.z; qT[(dq*4+3)*68 + a] = q4.w;
    kT[(dq*4+0)*68 + a] = k4.x; kT[(dq*4+1)*68 + a] = k4.y;
    kT[(dq*4+2)*68 + a] = k4.z; kT[(dq*4+3)*68 + a] = k4.w;
    *(float4*)(vs + a*20 + dq*4) = v4;
  }
  if (t < 64) cm[t] = ws[WS_CM + t];
  __syncthreads();
  // scores: 4x4 register outer product -> sc[a][b]
  {
    const int ta = t & 15, tb = t >> 4;
    float sa[4][4];
#pragma unroll
    for (int r = 0; r < 4; ++r)
#pragma unroll
      for (int c = 0; c < 4; ++c) sa[r][c] = 0.f;
#pragma unroll
    for (int d = 0; d < 16; ++d) {
      float4 qv = *(float4*)(qT + d*68 + ta*4);
      float4 kv = *(float4*)(kT + d*68 + tb*4);
      float qr[4] = {qv.x,qv.y,qv.z,qv.w};
      float kc[4] = {kv.x,kv.y,kv.z,kv.w};
#pragma unroll
      for (int r = 0; r < 4; ++r)
#pragma unroll
        for (int c = 0; c < 4; ++c) sa[r][c] = fmaf(qr[r], kc[c], sa[r][c]);
    }
#pragma unroll
    for (int r = 0; r < 4; ++r)
      *(float4*)(sc + (ta*4+r)*68 + tb*4) =
          make_float4(sa[r][0]*0.25f, sa[r][1]*0.25f,
                      sa[r][2]*0.25f, sa[r][3]*0.25f);
  }
  __syncthreads();
  // weighted softmax row a, normalized in-place in sc
  {
    float pv[16], cmv[16];
#pragma unroll
    for (int i4 = 0; i4 < 4; ++i4) {
      float4 v = *(float4*)(sc + a*68 + dq*16 + i4*4);
      pv[i4*4+0] = v.x; pv[i4*4+1] = v.y; pv[i4*4+2] = v.z; pv[i4*4+3] = v.w;
    }
#pragma unroll
    for (int i = 0; i < 16; ++i) cmv[i] = cm[dq*16 + i];
    float Mx = -1e30f;
#pragma unroll
    for (int i = 0; i < 16; ++i) if (cmv[i] > 0.f) Mx = fmaxf(Mx, pv[i]);
    Mx = fmaxf(Mx, __shfl_xor(Mx, 1));
    Mx = fmaxf(Mx, __shfl_xor(Mx, 2));
    float z = 0.f;
#pragma unroll
    for (int i = 0; i < 16; ++i) {
      float e = (cmv[i] > 0.f) ? cmv[i]*__expf(pv[i]-Mx) : 0.f;
      pv[i] = e; z += e;
    }
    z += __shfl_xor(z, 1);
    z += __shfl_xor(z, 2);
    float rz = 1.0f / z;
#pragma unroll
    for (int i4 = 0; i4 < 4; ++i4)
      *(float4*)(sc + a*68 + dq*16 + i4*4) =
          make_float4(pv[i4*4+0]*rz, pv[i4*4+1]*rz,
                      pv[i4*4+2]*rz, pv[i4*4+3]*rz);
  }
  __syncthreads();
  // PV: wave g owns rows g*16..g*16+15; lane quad spans d
  {
    const int g = t >> 6, l = t & 63;
    const int ar = g*16 + (l >> 2), d4 = (l & 3)*4;
    float o0 = 0.f, o1 = 0.f, o2 = 0.f, o3 = 0.f;
#pragma unroll 4
    for (int b4 = 0; b4 < 64; b4 += 4) {
      float4 p4 = *(float4*)(sc + ar*68 + b4);
      float4 va = *(float4*)(vs + (b4+0)*20 + d4);
      float4 vb = *(float4*)(vs + (b4+1)*20 + d4);
      float4 vc = *(float4*)(vs + (b4+2)*20 + d4);
      float4 vd = *(float4*)(vs + (b4+3)*20 + d4);
      o0 = fmaf(p4.x, va.x, fmaf(p4.y, vb.x, fmaf(p4.z, vc.x, fmaf(p4.w, vd.x, o0))));
      o1 = fmaf(p4.x, va.y, fmaf(p4.y, vb.y, fmaf(p4.z, vc.y, fmaf(p4.w, vd.y, o1))));
      o2 = fmaf(p4.x, va.z, fmaf(p4.y, vb.z, fmaf(p4.z, vc.z, fmaf(p4.w, vd.z, o2))));
      o3 = fmaf(p4.x, va.w, fmaf(p4.y, vb.w, fmaf(p4.z, vc.w, fmaf(p4.w, vd.w, o3))));
    }
    const float fwS = fw[s];
    float* dst = ws + WS_OPART + (size_t)s*(H_*B_*16) + h*(B_*16) + t*4;
    *(float4*)dst = make_float4(fwS*o0, fwS*o1, fwS*o2, fwS*o3);
  }
}

// ============ K3: reduce O_part + logits + lse + weighted-CE per row =======
__global__ __launch_bounds__(256) void k_final(
    const float* __restrict__ ws, float* __restrict__ out) {
  const int aa = blockIdx.x, t = threadIdx.x;
  __shared__ float oh[256], lg[64];
  {
    const float* op = ws + WS_OPART + (t>>4)*(B_*16) + aa*16 + (t&15);
    float acc = 0.f;
#pragma unroll
    for (int s = 0; s < S_; ++s) acc += op[(size_t)s*(H_*B_*16)];
    oh[t] = acc;
  }
  __syncthreads();
  const int k = t >> 2, q = t & 3;
  if (k < KC_) {
    float lv = 0.f;
    const float4* M4 = (const float4*)(ws + WS_M + k*E_ + q*64);
    const float4* o4 = (const float4*)(oh + q*64);
#pragma unroll
    for (int j = 0; j < 16; ++j) {
      float4 m = M4[j], o = o4[j];
      lv = fmaf(m.x, o.x, lv); lv = fmaf(m.y, o.y, lv);
      lv = fmaf(m.z, o.z, lv); lv = fmaf(m.w, o.w, lv);
    }
    lv += __shfl_xor(lv, 1);
    lv += __shfl_xor(lv, 2);
    if (q == 0) lg[k] = lv + ws[WS_C + k];
  }
  __syncthreads();
  if (t < 64) {
    float x = (t < KC_) ? lg[t] : -1e30f;
    float Mx = x;
#pragma unroll
    for (int off = 1; off < 64; off <<= 1) Mx = fmaxf(Mx, __shfl_xor(Mx, off));
    float z = (t < KC_) ? __expf(x - Mx) : 0.f;
#pragma unroll
    for (int off = 1; off < 64; off <<= 1) z += __shfl_xor(z, off);
    float lse = Mx + __logf(z);
    float term = (t < KC_) ? ws[WS_WK + aa*KC_ + t] * (lse - x) : 0.f;
#pragma unroll
    for (int off = 1; off < 64; off <<= 1) term += __shfl_xor(term, off);
    if (t == 0) atomicAdd(out, term * ws[WS_INVDEN]);
  }
}

extern "C" void kernel_launch(void* const* d_in, const int* in_sizes, int n_in,
                              void* d_out, int out_size, void* d_ws, size_t ws_size,
                              hipStream_t stream) {
  const float* feat    = (const float*)d_in[0];
  const int*   labels0 = (const int*)d_in[1];
  const int*   labels1 = (const int*)d_in[2];
  const float* ipw     = (const float*)d_in[3];
  const float* ipb     = (const float*)d_in[4];
  const float* opw     = (const float*)d_in[5];
  const float* opb     = (const float*)d_in[6];
  const float* fw      = (const float*)d_in[7];
  const float* fbi     = (const float*)d_in[8];
  const float* hw      = (const float*)d_in[9];
  const float* hb      = (const float*)d_in[10];
  float* out = (float*)d_out;
  float* ws  = (float*)d_ws;

  k_prep<<<96, 256, 0, stream>>>(ipw, labels0, labels1, opw, opb, fw, fbi,
                                 hw, hb, ws, out);
  k_proj<<<512, 256, 0, stream>>>(feat, ipb, ws);
  k_attn<<<512, 256, 0, stream>>>(ws, fw);
  k_final<<<64, 256, 0, stream>>>(ws, out);
}

// Round 6
// 114.024 us; speedup vs baseline: 2.9385x; 1.2863x over previous
//
#include <hip/hip_runtime.h>
#include <math.h>

#define B_ 64
#define E_ 256
#define S_ 32
#define H_ 16
#define P_ 512
#define KC_ 46
#define QKV_N (B_*S_*E_)   // 524288 floats per Q/K/V region

// workspace float offsets (float4-aligned)
#define WS_CM     0        // 64    key multiplicities
#define WS_WK     256      // 2944  Wk[64][46] per-row class weights
#define WS_INVDEN 3328     // 1
#define WS_C      3392     // 46    logit constant c[k]
#define WS_M      3584     // 11776 M[46][256] = Hw @ Wout
#define WS_WB     16384    // 98304 float-slots: Wb[768][256] bf16
#define WS_XT     114688   // 262144 float-slots: XT[64][32][256] bf16
#define WS_QKV    376832   // 3*524288 fp32 Q,K,V
#define WS_OPART  1949696  // 524288 O_part[32][16][64][16]  (s,h,a,d)

typedef short bf16x8 __attribute__((ext_vector_type(8)));
typedef float f32x4  __attribute__((ext_vector_type(4)));

__device__ __forceinline__ ushort f2bf(float f) {
  unsigned u = __float_as_uint(f);
  u = (u + 0x7FFFu + ((u >> 16) & 1u)) >> 16;   // RNE
  return (ushort)u;
}

// ============ K0: prep: Wb convert | XT transpose-convert | pairs | M,c ====
__global__ __launch_bounds__(256) void k_prep(
    const float* __restrict__ feat, const float* __restrict__ w,
    const int* __restrict__ labels0, const int* __restrict__ labels1,
    const float* __restrict__ wout, const float* __restrict__ bout,
    const float* __restrict__ fw, const float* __restrict__ fbi,
    const float* __restrict__ hw, const float* __restrict__ hb,
    float* __restrict__ ws, float* __restrict__ out) {
  __shared__ float sm[8448];
  const int bid = blockIdx.x, t = threadIdx.x;
  if (bid < 24) {
    // ---- convert in_proj_w [768][256] fp32 -> Wb bf16 (straight copy) ----
    const float4* src = (const float4*)w;       // 49152 float4s
    ushort* dstW = (ushort*)(ws + WS_WB);
#pragma unroll
    for (int i = 0; i < 8; ++i) {
      int idx = bid*2048 + i*256 + t;
      float4 v = src[idx];
      ushort4 o;
      o.x = f2bf(v.x); o.y = f2bf(v.y); o.z = f2bf(v.z); o.w = f2bf(v.w);
      *(ushort4*)(dstW + (size_t)idx*4) = o;
    }
  } else if (bid < 88) {
    // ---- transpose-convert feat[b][e][s] -> XT[b][s][e] bf16 ----
    const int b = bid - 24;
    const float4* fb = (const float4*)(feat + (size_t)b*(E_*S_));
#pragma unroll
    for (int i = 0; i < 8; ++i) {
      int idx = i*256 + t; int e = idx >> 3, s4 = (idx & 7)*4;
      float4 v = fb[idx];
      sm[e*33 + s4+0] = v.x; sm[e*33 + s4+1] = v.y;
      sm[e*33 + s4+2] = v.z; sm[e*33 + s4+3] = v.w;
    }
    __syncthreads();
    const int s = t & 31, ec = (t >> 5) * 32;   // lanes span s: LDS conflict-free
    ushort* dstX = (ushort*)(ws + WS_XT) + (size_t)b*(S_*E_) + s*E_ + ec;
#pragma unroll
    for (int g = 0; g < 4; ++g) {
      ushort tmp[8];
#pragma unroll
      for (int u = 0; u < 8; ++u) tmp[u] = f2bf(sm[(ec + g*8 + u)*33 + s]);
      *(uint4*)(dstX + g*8) = *(uint4*)tmp;
    }
  } else if (bid == 88) {
    // ---- pair selection, class ids, Wk, cm, inv_den ----
    float* csh = sm;                  // 64
    float* cls = sm + 64;             // 46
    float* wsh = sm + 112;            // 46
    float* den = sm + 160;            // 1
    float* Wk  = sm + 192;            // 2944
    int* scan = (int*)(sm + 3200);    // 256
    int* l0   = (int*)(sm + 3456);    // 64
    int* l1   = (int*)(sm + 3520);    // 64
    int* seli = (int*)(sm + 3584);    // 512
    int* selj = (int*)(sm + 4096);    // 512
    if (t < 64) { l0[t] = labels0[t]; l1[t] = labels1[t]; csh[t] = 0.f; }
    if (t < KC_) cls[t] = 0.f;
    if (t == 0) den[0] = 0.f;
    for (int i = t; i < 2944; i += 256) Wk[i] = 0.f;
    __syncthreads();
    unsigned bits = 0; int c = 0;
    for (int u = 0; u < 16; ++u) {    // contiguous 16-chunk keeps row-major order
      int idx = t*16 + u;
      if (l1[idx>>6] == l1[idx&63]) { bits |= 1u<<u; ++c; }
    }
    scan[t] = c; __syncthreads();
    for (int off = 1; off < 256; off <<= 1) {
      int v = (t >= off) ? scan[t-off] : 0;
      __syncthreads();
      scan[t] += v;
      __syncthreads();
    }
    const int total = scan[255];
    int rank = scan[t] - c;           // exclusive prefix
    for (int p = t; p < P_; p += 256)
      if (p >= total) { seli[p] = 0; selj[p] = 0; }   // fill_value=0
    for (int u = 0; u < 16; ++u) {
      if (bits & (1u<<u)) {
        if (rank < P_) { int idx = t*16+u; seli[rank] = idx>>6; selj[rank] = idx&63; }
        ++rank;
      }
    }
    __syncthreads();
    int ii[2], yy[2]; float vv[2];
#pragma unroll
    for (int r = 0; r < 2; ++r) {
      int p = t + r*256;
      int i = seli[p], j = selj[p];
      atomicAdd(&csh[j], 1.0f);       // multiplicity incl. padding pairs
      int la = l0[i], lb = l0[j];
      int y;
      if (la == lb) y = 0;
      else {
        int lo = la < lb ? la : lb, hi = la < lb ? lb : la;
        y = 1 + lo*9 - (lo*(lo-1))/2 + (hi-lo-1);
      }
      float v = (p < total) ? 1.f : 0.f;
      if (v > 0.f) atomicAdd(&cls[y], 1.f);
      ii[r] = i; yy[r] = y; vv[r] = v;
    }
    __syncthreads();
    if (t < KC_) {
      float cv = cls[t];
      wsh[t] = cv > 0.f ? 1.0f/cv : 0.f;
      if (cv > 0.f) atomicAdd(den, 1.0f);   // sum(wy) == #present classes
    }
    __syncthreads();
#pragma unroll
    for (int r = 0; r < 2; ++r)
      if (vv[r] > 0.f) atomicAdd(&Wk[ii[r]*KC_ + yy[r]], wsh[yy[r]]);
    __syncthreads();
    if (t < 64) ws[WS_CM + t] = csh[t];
    for (int i = t; i < 2944; i += 256) ws[WS_WK + i] = Wk[i];
    if (t == 0) ws[WS_INVDEN] = 1.0f / den[0];
  } else if (bid < 135) {
    // ---- M[k,:] = hw[k,:] @ Wout  and  c[k] ----
    int k = bid - 89;
    float* hwsh = sm;                 // 256
    float* redA = sm + 256;           // 256
    float* redB = sm + 512;           // 256
    hwsh[t] = hw[k*E_ + t];
    __syncthreads();
    float a0 = 0.f;
#pragma unroll 8
    for (int e = 0; e < E_; ++e) a0 = fmaf(hwsh[e], wout[e*E_ + t], a0);
    ws[WS_M + k*E_ + t] = a0;
    redA[t] = hwsh[t];
    redB[t] = hwsh[t]*bout[t];
    __syncthreads();
    for (int off = 128; off > 0; off >>= 1) {
      if (t < off) { redA[t] += redA[t+off]; redB[t] += redB[t+off]; }
      __syncthreads();
    }
    if (t == 0) {
      float sfw = 0.f;
      for (int s = 0; s < S_; ++s) sfw += fw[s];
      ws[WS_C + k] = fbi[0]*redA[0] + sfw*redB[0] + hb[k];
    }
  } else {
    if (t == 0) out[0] = 0.f;
  }
}

// ============ K1: QKV projection via bf16 MFMA, frags from global ==========
// grid 512 = 64 b x 8 job-groups; wave computes 3 16x16 C-tiles (out x s)
__global__ __launch_bounds__(256) void k_proj(
    const float* __restrict__ bias, float* __restrict__ ws) {
  const int bid = blockIdx.x, t = threadIdx.x;
  const int b = bid >> 3, w = t >> 6, L = t & 63;
  const int lane16 = L & 15, quad = L >> 4;
  const short* WB  = (const short*)(ws + WS_WB);
  const short* XTb = (const short*)(ws + WS_XT) + (size_t)b*(S_*E_);
#pragma unroll
  for (int i = 0; i < 3; ++i) {
    const int j = (bid & 7)*12 + w*3 + i;   // 0..95 = 48 out-tiles x 2 s-tiles
    const int ot = j >> 1, st = j & 1;
    const int out0 = ot*16;
    const short* arow = WB  + (size_t)(out0 + lane16)*E_ + quad*8;
    const short* brow = XTb + (size_t)(st*16 + lane16)*E_ + quad*8;
    f32x4 acc = {0.f, 0.f, 0.f, 0.f};
#pragma unroll
    for (int k = 0; k < 8; ++k) {
      bf16x8 av = *(const bf16x8*)(arow + k*32);
      bf16x8 bv = *(const bf16x8*)(brow + k*32);
      acc = __builtin_amdgcn_mfma_f32_16x16x32_bf16(av, bv, acc, 0, 0, 0);
    }
    // C[row=out_local][col=s_local]: row = quad*4+r, col = lane16
    const int rgn = out0 >> 8;                 // q/k/v region (tile never crosses)
    const int s = st*16 + lane16;
    const int e0 = (out0 & 255) + quad*4;      // 4 consecutive e per lane
    float4 bb = *(const float4*)(bias + out0 + quad*4);
    float* dst = ws + WS_QKV + (size_t)rgn*QKV_N + (size_t)b*(S_*E_) + s*E_ + e0;
    *(float4*)dst = make_float4(acc[0]+bb.x, acc[1]+bb.y, acc[2]+bb.z, acc[3]+bb.w);
  }
}

// ============ K2: weighted attention per (s,h); exclusive O_part ===========
__global__ __launch_bounds__(256) void k_attn(
    float* __restrict__ ws, const float* __restrict__ fw) {
  __shared__ float qT[16*68], kT[16*68], vs[64*20], sc[64*68], cm[64];
  const int s = blockIdx.x >> 4, h = blockIdx.x & 15;
  const int t = threadIdx.x;
  const int a = t >> 2, dq = t & 3;
  const float* qkv = ws + WS_QKV;
  {
    size_t off = (size_t)a*(S_*E_) + (size_t)s*E_ + h*16 + dq*4;
    float4 q4 = *(const float4*)(qkv + off);
    float4 k4 = *(const float4*)(qkv + QKV_N + off);
    float4 v4 = *(const float4*)(qkv + 2*(size_t)QKV_N + off);
    qT[(dq*4+0)*68 + a] = q4.x; qT[(dq*4+1)*68 + a] = q4.y;
    qT[(dq*4+2)*68 + a] = q4.z; qT[(dq*4+3)*68 + a] = q4.w;
    kT[(dq*4+0)*68 + a] = k4.x; kT[(dq*4+1)*68 + a] = k4.y;
    kT[(dq*4+2)*68 + a] = k4.z; kT[(dq*4+3)*68 + a] = k4.w;
    *(float4*)(vs + a*20 + dq*4) = v4;
  }
  if (t < 64) cm[t] = ws[WS_CM + t];
  __syncthreads();
  // scores: 4x4 register outer product -> sc[a][b]
  {
    const int ta = t & 15, tb = t >> 4;
    float sa[4][4];
#pragma unroll
    for (int r = 0; r < 4; ++r)
#pragma unroll
      for (int c = 0; c < 4; ++c) sa[r][c] = 0.f;
#pragma unroll
    for (int d = 0; d < 16; ++d) {
      float4 qv = *(float4*)(qT + d*68 + ta*4);
      float4 kv = *(float4*)(kT + d*68 + tb*4);
      float qr[4] = {qv.x,qv.y,qv.z,qv.w};
      float kc[4] = {kv.x,kv.y,kv.z,kv.w};
#pragma unroll
      for (int r = 0; r < 4; ++r)
#pragma unroll
        for (int c = 0; c < 4; ++c) sa[r][c] = fmaf(qr[r], kc[c], sa[r][c]);
    }
#pragma unroll
    for (int r = 0; r < 4; ++r)
      *(float4*)(sc + (ta*4+r)*68 + tb*4) =
          make_float4(sa[r][0]*0.25f, sa[r][1]*0.25f,
                      sa[r][2]*0.25f, sa[r][3]*0.25f);
  }
  __syncthreads();
  // weighted softmax row a, normalized in-place in sc
  {
    float pv[16], cmv[16];
#pragma unroll
    for (int i4 = 0; i4 < 4; ++i4) {
      float4 v = *(float4*)(sc + a*68 + dq*16 + i4*4);
      pv[i4*4+0] = v.x; pv[i4*4+1] = v.y; pv[i4*4+2] = v.z; pv[i4*4+3] = v.w;
    }
#pragma unroll
    for (int i = 0; i < 16; ++i) cmv[i] = cm[dq*16 + i];
    float Mx = -1e30f;
#pragma unroll
    for (int i = 0; i < 16; ++i) if (cmv[i] > 0.f) Mx = fmaxf(Mx, pv[i]);
    Mx = fmaxf(Mx, __shfl_xor(Mx, 1));
    Mx = fmaxf(Mx, __shfl_xor(Mx, 2));
    float z = 0.f;
#pragma unroll
    for (int i = 0; i < 16; ++i) {
      float e = (cmv[i] > 0.f) ? cmv[i]*__expf(pv[i]-Mx) : 0.f;
      pv[i] = e; z += e;
    }
    z += __shfl_xor(z, 1);
    z += __shfl_xor(z, 2);
    float rz = 1.0f / z;
#pragma unroll
    for (int i4 = 0; i4 < 4; ++i4)
      *(float4*)(sc + a*68 + dq*16 + i4*4) =
          make_float4(pv[i4*4+0]*rz, pv[i4*4+1]*rz,
                      pv[i4*4+2]*rz, pv[i4*4+3]*rz);
  }
  __syncthreads();
  // PV: wave g owns rows g*16..g*16+15; lane quad spans d
  {
    const int g = t >> 6, l = t & 63;
    const int ar = g*16 + (l >> 2), d4 = (l & 3)*4;
    float o0 = 0.f, o1 = 0.f, o2 = 0.f, o3 = 0.f;
#pragma unroll 4
    for (int b4 = 0; b4 < 64; b4 += 4) {
      float4 p4 = *(float4*)(sc + ar*68 + b4);
      float4 va = *(float4*)(vs + (b4+0)*20 + d4);
      float4 vb = *(float4*)(vs + (b4+1)*20 + d4);
      float4 vc = *(float4*)(vs + (b4+2)*20 + d4);
      float4 vd = *(float4*)(vs + (b4+3)*20 + d4);
      o0 = fmaf(p4.x, va.x, fmaf(p4.y, vb.x, fmaf(p4.z, vc.x, fmaf(p4.w, vd.x, o0))));
      o1 = fmaf(p4.x, va.y, fmaf(p4.y, vb.y, fmaf(p4.z, vc.y, fmaf(p4.w, vd.y, o1))));
      o2 = fmaf(p4.x, va.z, fmaf(p4.y, vb.z, fmaf(p4.z, vc.z, fmaf(p4.w, vd.z, o2))));
      o3 = fmaf(p4.x, va.w, fmaf(p4.y, vb.w, fmaf(p4.z, vc.w, fmaf(p4.w, vd.w, o3))));
    }
    const float fwS = fw[s];
    float* dst = ws + WS_OPART + (size_t)s*(H_*B_*16) + h*(B_*16) + t*4;
    *(float4*)dst = make_float4(fwS*o0, fwS*o1, fwS*o2, fwS*o3);
  }
}

// ============ K3: reduce O_part + logits + lse + weighted-CE per row =======
__global__ __launch_bounds__(256) void k_final(
    const float* __restrict__ ws, float* __restrict__ out) {
  const int aa = blockIdx.x, t = threadIdx.x;
  __shared__ float oh[256], lg[64];
  {
    const float* op = ws + WS_OPART + (t>>4)*(B_*16) + aa*16 + (t&15);
    float acc = 0.f;
#pragma unroll
    for (int s = 0; s < S_; ++s) acc += op[(size_t)s*(H_*B_*16)];
    oh[t] = acc;
  }
  __syncthreads();
  const int k = t >> 2, q = t & 3;
  if (k < KC_) {
    float lv = 0.f;
    const float4* M4 = (const float4*)(ws + WS_M + k*E_ + q*64);
    const float4* o4 = (const float4*)(oh + q*64);
#pragma unroll
    for (int j = 0; j < 16; ++j) {
      float4 m = M4[j], o = o4[j];
      lv = fmaf(m.x, o.x, lv); lv = fmaf(m.y, o.y, lv);
      lv = fmaf(m.z, o.z, lv); lv = fmaf(m.w, o.w, lv);
    }
    lv += __shfl_xor(lv, 1);
    lv += __shfl_xor(lv, 2);
    if (q == 0) lg[k] = lv + ws[WS_C + k];
  }
  __syncthreads();
  if (t < 64) {
    float x = (t < KC_) ? lg[t] : -1e30f;
    float Mx = x;
#pragma unroll
    for (int off = 1; off < 64; off <<= 1) Mx = fmaxf(Mx, __shfl_xor(Mx, off));
    float z = (t < KC_) ? __expf(x - Mx) : 0.f;
#pragma unroll
    for (int off = 1; off < 64; off <<= 1) z += __shfl_xor(z, off);
    float lse = Mx + __logf(z);
    float term = (t < KC_) ? ws[WS_WK + aa*KC_ + t] * (lse - x) : 0.f;
#pragma unroll
    for (int off = 1; off < 64; off <<= 1) term += __shfl_xor(term, off);
    if (t == 0) atomicAdd(out, term * ws[WS_INVDEN]);
  }
}

extern "C" void kernel_launch(void* const* d_in, const int* in_sizes, int n_in,
                              void* d_out, int out_size, void* d_ws, size_t ws_size,
                              hipStream_t stream) {
  const float* feat    = (const float*)d_in[0];
  const int*   labels0 = (const int*)d_in[1];
  const int*   labels1 = (const int*)d_in[2];
  const float* ipw     = (const float*)d_in[3];
  const float* ipb     = (const float*)d_in[4];
  const float* opw     = (const float*)d_in[5];
  const float* opb     = (const float*)d_in[6];
  const float* fw      = (const float*)d_in[7];
  const float* fbi     = (const float*)d_in[8];
  const float* hw      = (const float*)d_in[9];
  const float* hb      = (const float*)d_in[10];
  float* out = (float*)d_out;
  float* ws  = (float*)d_ws;

  k_prep<<<136, 256, 0, stream>>>(feat, ipw, labels0, labels1, opw, opb, fw,
                                  fbi, hw, hb, ws, out);
  k_proj<<<512, 256, 0, stream>>>(ipb, ws);
  k_attn<<<512, 256, 0, stream>>>(ws, fw);
  k_final<<<64, 256, 0, stream>>>(ws, out);
}

// Round 7
// 105.355 us; speedup vs baseline: 3.1803x; 1.0823x over previous
//
#include <hip/hip_runtime.h>
#include <math.h>

#define B_ 64
#define E_ 256
#define S_ 32
#define H_ 16
#define P_ 512
#define KC_ 46

// workspace float offsets (float4-aligned)
#define WS_CM     0        // 64    key multiplicities
#define WS_WK     256      // 2944  Wk[64][46] per-row class weights
#define WS_INVDEN 3328     // 1
#define WS_C      3392     // 46    logit constant c[k]
#define WS_M      3584     // 11776 M[46][256] = Hw @ Wout
#define WS_WB     16384    // 98304 float-slots: Wb[768][256] bf16
#define WS_XF     114688   // 262144 float-slots: XF[32][64][256] bf16 (s,b,e)
#define WS_OPART  1949696  // 524288 O_part[32][16][64][16]  (s,h,a,d)

typedef short bf16x8 __attribute__((ext_vector_type(8)));
typedef float f32x4  __attribute__((ext_vector_type(4)));

__device__ __forceinline__ ushort f2bf(float f) {
  unsigned u = __float_as_uint(f);
  u = (u + 0x7FFFu + ((u >> 16) & 1u)) >> 16;   // RNE
  return (ushort)u;
}

// ============ K0: prep: Wb convert | XF transpose-convert | pairs | M,c ====
__global__ __launch_bounds__(256) void k_prep(
    const float* __restrict__ feat, const float* __restrict__ w,
    const int* __restrict__ labels0, const int* __restrict__ labels1,
    const float* __restrict__ wout, const float* __restrict__ bout,
    const float* __restrict__ fw, const float* __restrict__ fbi,
    const float* __restrict__ hw, const float* __restrict__ hb,
    float* __restrict__ ws, float* __restrict__ out) {
  __shared__ float sm[8448];
  const int bid = blockIdx.x, t = threadIdx.x;
  if (bid < 24) {
    // ---- convert in_proj_w [768][256] fp32 -> Wb bf16 (straight copy) ----
    const float4* src = (const float4*)w;       // 49152 float4s
    ushort* dstW = (ushort*)(ws + WS_WB);
#pragma unroll
    for (int i = 0; i < 8; ++i) {
      int idx = bid*2048 + i*256 + t;
      float4 v = src[idx];
      ushort4 o;
      o.x = f2bf(v.x); o.y = f2bf(v.y); o.z = f2bf(v.z); o.w = f2bf(v.w);
      *(ushort4*)(dstW + (size_t)idx*4) = o;
    }
  } else if (bid < 88) {
    // ---- transpose-convert feat[b][e][s] -> XF[s][b][e] bf16 ----
    const int b = bid - 24;
    const float4* fb = (const float4*)(feat + (size_t)b*(E_*S_));
#pragma unroll
    for (int i = 0; i < 8; ++i) {
      int idx = i*256 + t; int e = idx >> 3, s4 = (idx & 7)*4;
      float4 v = fb[idx];
      sm[e*33 + s4+0] = v.x; sm[e*33 + s4+1] = v.y;
      sm[e*33 + s4+2] = v.z; sm[e*33 + s4+3] = v.w;
    }
    __syncthreads();
    const int s = t >> 3, eb = (t & 7) * 32;    // lanes span e: coalesced stores
    ushort* dstX = (ushort*)(ws + WS_XF) + (size_t)s*(B_*E_) + (size_t)b*E_ + eb;
#pragma unroll
    for (int g = 0; g < 4; ++g) {
      ushort tmp[8];
#pragma unroll
      for (int u = 0; u < 8; ++u) tmp[u] = f2bf(sm[(eb + g*8 + u)*33 + s]);
      *(uint4*)(dstX + g*8) = *(uint4*)tmp;
    }
  } else if (bid == 88) {
    // ---- pair selection, class ids, Wk, cm, inv_den ----
    float* csh = sm;                  // 64
    float* cls = sm + 64;             // 46
    float* wsh = sm + 112;            // 46
    float* den = sm + 160;            // 1
    float* Wk  = sm + 192;            // 2944
    int* scan = (int*)(sm + 3200);    // 256
    int* l0   = (int*)(sm + 3456);    // 64
    int* l1   = (int*)(sm + 3520);    // 64
    int* seli = (int*)(sm + 3584);    // 512
    int* selj = (int*)(sm + 4096);    // 512
    if (t < 64) { l0[t] = labels0[t]; l1[t] = labels1[t]; csh[t] = 0.f; }
    if (t < KC_) cls[t] = 0.f;
    if (t == 0) den[0] = 0.f;
    for (int i = t; i < 2944; i += 256) Wk[i] = 0.f;
    __syncthreads();
    unsigned bits = 0; int c = 0;
    for (int u = 0; u < 16; ++u) {    // contiguous 16-chunk keeps row-major order
      int idx = t*16 + u;
      if (l1[idx>>6] == l1[idx&63]) { bits |= 1u<<u; ++c; }
    }
    scan[t] = c; __syncthreads();
    for (int off = 1; off < 256; off <<= 1) {
      int v = (t >= off) ? scan[t-off] : 0;
      __syncthreads();
      scan[t] += v;
      __syncthreads();
    }
    const int total = scan[255];
    int rank = scan[t] - c;           // exclusive prefix
    for (int p = t; p < P_; p += 256)
      if (p >= total) { seli[p] = 0; selj[p] = 0; }   // fill_value=0
    for (int u = 0; u < 16; ++u) {
      if (bits & (1u<<u)) {
        if (rank < P_) { int idx = t*16+u; seli[rank] = idx>>6; selj[rank] = idx&63; }
        ++rank;
      }
    }
    __syncthreads();
    int ii[2], yy[2]; float vv[2];
#pragma unroll
    for (int r = 0; r < 2; ++r) {
      int p = t + r*256;
      int i = seli[p], j = selj[p];
      atomicAdd(&csh[j], 1.0f);       // multiplicity incl. padding pairs
      int la = l0[i], lb = l0[j];
      int y;
      if (la == lb) y = 0;
      else {
        int lo = la < lb ? la : lb, hi = la < lb ? lb : la;
        y = 1 + lo*9 - (lo*(lo-1))/2 + (hi-lo-1);
      }
      float v = (p < total) ? 1.f : 0.f;
      if (v > 0.f) atomicAdd(&cls[y], 1.f);
      ii[r] = i; yy[r] = y; vv[r] = v;
    }
    __syncthreads();
    if (t < KC_) {
      float cv = cls[t];
      wsh[t] = cv > 0.f ? 1.0f/cv : 0.f;
      if (cv > 0.f) atomicAdd(den, 1.0f);   // sum(wy) == #present classes
    }
    __syncthreads();
#pragma unroll
    for (int r = 0; r < 2; ++r)
      if (vv[r] > 0.f) atomicAdd(&Wk[ii[r]*KC_ + yy[r]], wsh[yy[r]]);
    __syncthreads();
    if (t < 64) ws[WS_CM + t] = csh[t];
    for (int i = t; i < 2944; i += 256) ws[WS_WK + i] = Wk[i];
    if (t == 0) ws[WS_INVDEN] = 1.0f / den[0];
  } else if (bid < 135) {
    // ---- M[k,:] = hw[k,:] @ Wout  and  c[k] ----
    int k = bid - 89;
    float* hwsh = sm;                 // 256
    float* redA = sm + 256;           // 256
    float* redB = sm + 512;           // 256
    hwsh[t] = hw[k*E_ + t];
    __syncthreads();
    float a0 = 0.f;
#pragma unroll 8
    for (int e = 0; e < E_; ++e) a0 = fmaf(hwsh[e], wout[e*E_ + t], a0);
    ws[WS_M + k*E_ + t] = a0;
    redA[t] = hwsh[t];
    redB[t] = hwsh[t]*bout[t];
    __syncthreads();
    for (int off = 128; off > 0; off >>= 1) {
      if (t < off) { redA[t] += redA[t+off]; redB[t] += redB[t+off]; }
      __syncthreads();
    }
    if (t == 0) {
      float sfw = 0.f;
      for (int s = 0; s < S_; ++s) sfw += fw[s];
      ws[WS_C + k] = fbi[0]*redA[0] + sfw*redB[0] + hb[k];
    }
  } else {
    if (t == 0) out[0] = 0.f;
  }
}

// ============ K1: fused QKV-MFMA + weighted attention per (s,h) ============
// Wave w generates Q,K,V 16x16 C-tiles for a-tile w via mfma_16x16x32_bf16
// (same fragment pattern as verified R6 proj), stages into LDS, then the
// verified VALU softmax/PV runs unchanged. Bias + 1/sqrt(hd) folded in.
__global__ __launch_bounds__(256) void k_attn(
    const float* __restrict__ bias, const float* __restrict__ fw,
    float* __restrict__ ws) {
  __shared__ float qT[16*68], kT[16*68], vs[64*20], sc[64*68], cm[64];
  const int s = blockIdx.x >> 4, h = blockIdx.x & 15;
  const int t = threadIdx.x;
  const int w = t >> 6, L = t & 63, lane16 = L & 15, quad = L >> 4;
  const int a = t >> 2, dq = t & 3;
  // ---- MFMA QKV generation for a-tile w ----
  {
    const short* WB = (const short*)(ws + WS_WB);
    const short* XF = (const short*)(ws + WS_XF);
    const short* brow  = XF + (size_t)s*(B_*E_) + (size_t)(w*16 + lane16)*E_ + quad*8;
    const short* arowQ = WB + (size_t)(      h*16 + lane16)*E_ + quad*8;
    const short* arowK = WB + (size_t)(256 + h*16 + lane16)*E_ + quad*8;
    const short* arowV = WB + (size_t)(512 + h*16 + lane16)*E_ + quad*8;
    f32x4 accQ = {0.f,0.f,0.f,0.f}, accK = {0.f,0.f,0.f,0.f}, accV = {0.f,0.f,0.f,0.f};
#pragma unroll
    for (int k = 0; k < 8; ++k) {
      bf16x8 bv = *(const bf16x8*)(brow  + k*32);
      bf16x8 aq = *(const bf16x8*)(arowQ + k*32);
      bf16x8 ak = *(const bf16x8*)(arowK + k*32);
      bf16x8 av = *(const bf16x8*)(arowV + k*32);
      accQ = __builtin_amdgcn_mfma_f32_16x16x32_bf16(aq, bv, accQ, 0, 0, 0);
      accK = __builtin_amdgcn_mfma_f32_16x16x32_bf16(ak, bv, accK, 0, 0, 0);
      accV = __builtin_amdgcn_mfma_f32_16x16x32_bf16(av, bv, accV, 0, 0, 0);
    }
    // C[row=d=quad*4+r][col=a_local=lane16]; bias float4 at quad*4
    float4 bq = *(const float4*)(bias +        h*16 + quad*4);
    float4 bk = *(const float4*)(bias + 256 + h*16 + quad*4);
    float4 bv2 = *(const float4*)(bias + 512 + h*16 + quad*4);
    const float bqa[4] = {bq.x,bq.y,bq.z,bq.w};
    const float bka[4] = {bk.x,bk.y,bk.z,bk.w};
    const float bva[4] = {bv2.x,bv2.y,bv2.z,bv2.w};
    const int ag = w*16 + lane16;
#pragma unroll
    for (int r = 0; r < 4; ++r) {
      int d = quad*4 + r;
      qT[d*68 + ag] = (accQ[r] + bqa[r]) * 0.25f;   // fold 1/sqrt(16)
      kT[d*68 + ag] =  accK[r] + bka[r];
      vs[ag*20 + d] =  accV[r] + bva[r];
    }
  }
  if (t < 64) cm[t] = ws[WS_CM + t];
  __syncthreads();
  // ---- scores: 4x4 register outer product -> sc[a][b] ----
  {
    const int ta = t & 15, tb = t >> 4;
    float sa[4][4];
#pragma unroll
    for (int r = 0; r < 4; ++r)
#pragma unroll
      for (int c = 0; c < 4; ++c) sa[r][c] = 0.f;
#pragma unroll
    for (int d = 0; d < 16; ++d) {
      float4 qv = *(float4*)(qT + d*68 + ta*4);
      float4 kv = *(float4*)(kT + d*68 + tb*4);
      float qr[4] = {qv.x,qv.y,qv.z,qv.w};
      float kc[4] = {kv.x,kv.y,kv.z,kv.w};
#pragma unroll
      for (int r = 0; r < 4; ++r)
#pragma unroll
        for (int c = 0; c < 4; ++c) sa[r][c] = fmaf(qr[r], kc[c], sa[r][c]);
    }
#pragma unroll
    for (int r = 0; r < 4; ++r)
      *(float4*)(sc + (ta*4+r)*68 + tb*4) =
          make_float4(sa[r][0], sa[r][1], sa[r][2], sa[r][3]);
  }
  __syncthreads();
  // ---- weighted softmax row a, normalized in-place in sc ----
  {
    float pv[16], cmv[16];
#pragma unroll
    for (int i4 = 0; i4 < 4; ++i4) {
      float4 v = *(float4*)(sc + a*68 + dq*16 + i4*4);
      pv[i4*4+0] = v.x; pv[i4*4+1] = v.y; pv[i4*4+2] = v.z; pv[i4*4+3] = v.w;
    }
#pragma unroll
    for (int i = 0; i < 16; ++i) cmv[i] = cm[dq*16 + i];
    float Mx = -1e30f;
#pragma unroll
    for (int i = 0; i < 16; ++i) if (cmv[i] > 0.f) Mx = fmaxf(Mx, pv[i]);
    Mx = fmaxf(Mx, __shfl_xor(Mx, 1));
    Mx = fmaxf(Mx, __shfl_xor(Mx, 2));
    float z = 0.f;
#pragma unroll
    for (int i = 0; i < 16; ++i) {
      float e = (cmv[i] > 0.f) ? cmv[i]*__expf(pv[i]-Mx) : 0.f;
      pv[i] = e; z += e;
    }
    z += __shfl_xor(z, 1);
    z += __shfl_xor(z, 2);
    float rz = 1.0f / z;
#pragma unroll
    for (int i4 = 0; i4 < 4; ++i4)
      *(float4*)(sc + a*68 + dq*16 + i4*4) =
          make_float4(pv[i4*4+0]*rz, pv[i4*4+1]*rz,
                      pv[i4*4+2]*rz, pv[i4*4+3]*rz);
  }
  __syncthreads();
  // ---- PV: wave g owns rows g*16..g*16+15; lane quad spans d ----
  {
    const int g = t >> 6, l = t & 63;
    const int ar = g*16 + (l >> 2), d4 = (l & 3)*4;
    float o0 = 0.f, o1 = 0.f, o2 = 0.f, o3 = 0.f;
#pragma unroll 4
    for (int b4 = 0; b4 < 64; b4 += 4) {
      float4 p4 = *(float4*)(sc + ar*68 + b4);
      float4 va = *(float4*)(vs + (b4+0)*20 + d4);
      float4 vb = *(float4*)(vs + (b4+1)*20 + d4);
      float4 vc = *(float4*)(vs + (b4+2)*20 + d4);
      float4 vd = *(float4*)(vs + (b4+3)*20 + d4);
      o0 = fmaf(p4.x, va.x, fmaf(p4.y, vb.x, fmaf(p4.z, vc.x, fmaf(p4.w, vd.x, o0))));
      o1 = fmaf(p4.x, va.y, fmaf(p4.y, vb.y, fmaf(p4.z, vc.y, fmaf(p4.w, vd.y, o1))));
      o2 = fmaf(p4.x, va.z, fmaf(p4.y, vb.z, fmaf(p4.z, vc.z, fmaf(p4.w, vd.z, o2))));
      o3 = fmaf(p4.x, va.w, fmaf(p4.y, vb.w, fmaf(p4.z, vc.w, fmaf(p4.w, vd.w, o3))));
    }
    const float fwS = fw[s];
    float* dst = ws + WS_OPART + (size_t)s*(H_*B_*16) + h*(B_*16) + t*4;
    *(float4*)dst = make_float4(fwS*o0, fwS*o1, fwS*o2, fwS*o3);
  }
}

// ============ K2: reduce O_part + logits + lse + weighted-CE per row =======
__global__ __launch_bounds__(256) void k_final(
    const float* __restrict__ ws, float* __restrict__ out) {
  const int aa = blockIdx.x, t = threadIdx.x;
  __shared__ float oh[256], lg[64];
  {
    const float* op = ws + WS_OPART + (t>>4)*(B_*16) + aa*16 + (t&15);
    float acc = 0.f;
#pragma unroll
    for (int s = 0; s < S_; ++s) acc += op[(size_t)s*(H_*B_*16)];
    oh[t] = acc;
  }
  __syncthreads();
  const int k = t >> 2, q = t & 3;
  if (k < KC_) {
    float lv = 0.f;
    const float4* M4 = (const float4*)(ws + WS_M + k*E_ + q*64);
    const float4* o4 = (const float4*)(oh + q*64);
#pragma unroll
    for (int j = 0; j < 16; ++j) {
      float4 m = M4[j], o = o4[j];
      lv = fmaf(m.x, o.x, lv); lv = fmaf(m.y, o.y, lv);
      lv = fmaf(m.z, o.z, lv); lv = fmaf(m.w, o.w, lv);
    }
    lv += __shfl_xor(lv, 1);
    lv += __shfl_xor(lv, 2);
    if (q == 0) lg[k] = lv + ws[WS_C + k];
  }
  __syncthreads();
  if (t < 64) {
    float x = (t < KC_) ? lg[t] : -1e30f;
    float Mx = x;
#pragma unroll
    for (int off = 1; off < 64; off <<= 1) Mx = fmaxf(Mx, __shfl_xor(Mx, off));
    float z = (t < KC_) ? __expf(x - Mx) : 0.f;
#pragma unroll
    for (int off = 1; off < 64; off <<= 1) z += __shfl_xor(z, off);
    float lse = Mx + __logf(z);
    float term = (t < KC_) ? ws[WS_WK + aa*KC_ + t] * (lse - x) : 0.f;
#pragma unroll
    for (int off = 1; off < 64; off <<= 1) term += __shfl_xor(term, off);
    if (t == 0) atomicAdd(out, term * ws[WS_INVDEN]);
  }
}

extern "C" void kernel_launch(void* const* d_in, const int* in_sizes, int n_in,
                              void* d_out, int out_size, void* d_ws, size_t ws_size,
                              hipStream_t stream) {
  const float* feat    = (const float*)d_in[0];
  const int*   labels0 = (const int*)d_in[1];
  const int*   labels1 = (const int*)d_in[2];
  const float* ipw     = (const float*)d_in[3];
  const float* ipb     = (const float*)d_in[4];
  const float* opw     = (const float*)d_in[5];
  const float* opb     = (const float*)d_in[6];
  const float* fw      = (const float*)d_in[7];
  const float* fbi     = (const float*)d_in[8];
  const float* hw      = (const float*)d_in[9];
  const float* hb      = (const float*)d_in[10];
  float* out = (float*)d_out;
  float* ws  = (float*)d_ws;

  k_prep<<<136, 256, 0, stream>>>(feat, ipw, labels0, labels1, opw, opb, fw,
                                  fbi, hw, hb, ws, out);
  k_attn<<<512, 256, 0, stream>>>(ipb, fw, ws);
  k_final<<<64, 256, 0, stream>>>(ws, out);
}